// Round 1
// baseline (7808.437 us; speedup 1.0000x reference)
//
#include <hip/hip_runtime.h>

#define B_N 262144
#define T_STEPS 100
#define BETA_START 1e-4f
#define BETA_END 0.02f

typedef __bf16 bf16x8 __attribute__((ext_vector_type(8)));
typedef float f32x4 __attribute__((ext_vector_type(4)));

__device__ __forceinline__ float siluf(float z) {
  // z * sigmoid(z); native v_exp + v_rcp (2 trans ops)
  float e = __expf(-z);
  return z * __builtin_amdgcn_rcpf(1.0f + e);
}

__device__ __forceinline__ unsigned bbits(float f) {
  __bf16 h = (__bf16)f;
  return (unsigned)__builtin_bit_cast(unsigned short, h);
}
__device__ __forceinline__ unsigned pack2(float lo, float hi) {
  return bbits(lo) | (bbits(hi) << 16);
}
__device__ __forceinline__ float unlo(unsigned u) { return __uint_as_float(u << 16); }
__device__ __forceinline__ float unhi(unsigned u) { return __uint_as_float(u & 0xffff0000u); }

// Block: 256 threads = 4 waves; each wave owns 32 rows (2x 16-row MFMA tiles).
// Grid: B_N/128 = 2048 blocks.
__global__ __launch_bounds__(256, 2) void diff_kernel(
    const float* __restrict__ ctx, const float* __restrict__ x_init,
    const float* __restrict__ noise, const float* __restrict__ W1,
    const float* __restrict__ b1, const float* __restrict__ W2,
    const float* __restrict__ b2, const float* __restrict__ W3,
    const float* __restrict__ b3, const float* __restrict__ temb,
    float* __restrict__ out) {
  __shared__ alignas(16) unsigned short sW[128][136];  // W^T, bf16 bits, padded
  __shared__ float sx[128];                            // per-row x broadcast

  const int tid = threadIdx.x;
  const int lane = tid & 63;
  const int wv = tid >> 6;   // wave 0..3
  const int ar = lane & 15;  // A-frag row / C-frag col-low
  const int kg = lane >> 4;  // 0..3 k-group
  const int rowW = blockIdx.x * 128 + wv * 32;

  // ---- stage W1[:128]^T as bf16 ----
  for (int i = tid; i < 128 * 128; i += 256) {
    int k = i >> 7, n = i & 127;
    sW[n][k] = (unsigned short)bbits(W1[i]);
  }
  __syncthreads();

  // ---- per-lane constant vectors in C-layout columns ----
  float b1c[8], b2r[8], w3r[8];
#pragma unroll
  for (int nt = 0; nt < 8; ++nt) {
    b1c[nt] = b1[nt * 16 + ar];
    b2r[nt] = b2[nt * 16 + ar];
    w3r[nt] = W3[nt * 16 + ar];
  }

  // ---- C1 = ctx @ W1[:128] + b1 (bf16 MFMA) ----
  f32x4 acc[2][8];
#pragma unroll
  for (int t2 = 0; t2 < 2; ++t2)
#pragma unroll
    for (int nt = 0; nt < 8; ++nt)
      acc[t2][nt] = (f32x4){b1c[nt], b1c[nt], b1c[nt], b1c[nt]};

  {
    bf16x8 caf[2][4];
#pragma unroll
    for (int t2 = 0; t2 < 2; ++t2) {
      const float* crow = ctx + (size_t)(rowW + t2 * 16 + ar) * 128;
#pragma unroll
      for (int kk = 0; kk < 4; ++kk)
#pragma unroll
        for (int j = 0; j < 8; ++j)
          caf[t2][kk][j] = (__bf16)crow[kk * 32 + kg * 8 + j];
    }
#pragma unroll
    for (int kk = 0; kk < 4; ++kk)
#pragma unroll
      for (int nt = 0; nt < 8; ++nt) {
        bf16x8 bf = *reinterpret_cast<const bf16x8*>(&sW[nt * 16 + ar][kk * 32 + kg * 8]);
        acc[0][nt] = __builtin_amdgcn_mfma_f32_16x16x32_bf16(caf[0][kk], bf, acc[0][nt], 0, 0, 0);
        acc[1][nt] = __builtin_amdgcn_mfma_f32_16x16x32_bf16(caf[1][kk], bf, acc[1][nt], 0, 0, 0);
      }
  }
  __syncthreads();  // all waves done reading W1^T from LDS

  // ---- transpose C-layout -> A-layout via per-wave LDS scratch; pack bf16 pairs ----
  unsigned c1p[2][4][4];
  {
    float* scr = reinterpret_cast<float*>(&sW[0][0]) + wv * 2112;  // 16x132 f32 per wave
#pragma unroll
    for (int t2 = 0; t2 < 2; ++t2) {
#pragma unroll
      for (int nt = 0; nt < 8; ++nt)
#pragma unroll
        for (int r = 0; r < 4; ++r)
          scr[(kg * 4 + r) * 132 + nt * 16 + ar] = acc[t2][nt][r];
      asm volatile("s_waitcnt lgkmcnt(0)" ::: "memory");
#pragma unroll
      for (int kk = 0; kk < 4; ++kk)
#pragma unroll
        for (int jj = 0; jj < 4; ++jj) {
          float f0 = scr[ar * 132 + kk * 32 + kg * 8 + jj * 2];
          float f1 = scr[ar * 132 + kk * 32 + kg * 8 + jj * 2 + 1];
          c1p[t2][kk][jj] = pack2(f0, f1);
        }
      asm volatile("s_waitcnt lgkmcnt(0)" ::: "memory");
    }
  }
  __syncthreads();  // scratch reads done

  // ---- stage W2^T as bf16 ----
  for (int i = tid; i < 128 * 128; i += 256) {
    int k = i >> 7, n = i & 127;
    sW[n][k] = (unsigned short)bbits(W2[i]);
  }

  // ---- w1x / w1t packed pairs (rows 128,129 of W1) ----
  unsigned wxt[4][8];
#pragma unroll
  for (int kk = 0; kk < 4; ++kk)
#pragma unroll
    for (int j = 0; j < 8; ++j) {
      int c = kk * 32 + kg * 8 + j;
      wxt[kk][j] = pack2(W1[128 * 128 + c], W1[129 * 128 + c]);
    }

  // ---- x init (every lane holds its group's 4 rows per tile) ----
  float xq[2][4];
#pragma unroll
  for (int t2 = 0; t2 < 2; ++t2)
#pragma unroll
    for (int r = 0; r < 4; ++r)
      xq[t2][r] = x_init[rowW + t2 * 16 + kg * 4 + r];
  if (ar == 0) {
#pragma unroll
    for (int t2 = 0; t2 < 2; ++t2)
#pragma unroll
      for (int r = 0; r < 4; ++r)
        sx[wv * 32 + t2 * 16 + kg * 4 + r] = xq[t2][r];
  }

  // ---- diffusion schedule: acp at t=99 via forward product ----
  const float db = (BETA_END - BETA_START) / 99.0f;
  float acp = 1.0f;
  for (int t = 0; t < T_STEPS; ++t) acp *= (1.0f - (BETA_START + (float)t * db));
  const float b3v = b3[0];
  __syncthreads();  // W2^T staged; enter barrier-free main loop

  for (int t = T_STEPS - 1; t >= 0; --t) {
    const float beta = BETA_START + (float)t * db;
    const float alpha = 1.0f - beta;
    const float c_pred = beta * __builtin_amdgcn_rsqf(1.0f - acp);
    const float c_x = __builtin_amdgcn_rsqf(alpha);
    const float c_n = (t > 0) ? __builtin_amdgcn_sqrtf(beta) : 0.0f;
    const float te = temb[t];

    // scan index: step i = 99 - t uses noise[i]
    const size_t noff = (size_t)(T_STEPS - 1 - t) * B_N + rowW;
    const float eps0 = noise[noff + ar];
    const float eps1 = noise[noff + 16 + ar];
    const float xv0 = sx[wv * 32 + ar];
    const float xv1 = sx[wv * 32 + 16 + ar];

#pragma unroll
    for (int t2 = 0; t2 < 2; ++t2)
#pragma unroll
      for (int nt = 0; nt < 8; ++nt)
        acc[t2][nt] = (f32x4){b2r[nt], b2r[nt], b2r[nt], b2r[nt]};

#pragma unroll
    for (int kk = 0; kk < 4; ++kk) {
      bf16x8 af0, af1;
#pragma unroll
      for (int jj = 0; jj < 4; ++jj) {
        const unsigned cp0 = c1p[0][kk][jj], cp1 = c1p[1][kk][jj];
        const unsigned wpe = wxt[kk][2 * jj], wpo = wxt[kk][2 * jj + 1];
        const float wxe = unlo(wpe), wxo = unlo(wpo);
        const float ge = te * unhi(wpe), go = te * unhi(wpo);
        float z;
        z = fmaf(xv0, wxe, unlo(cp0) + ge); af0[2 * jj]     = (__bf16)siluf(z);
        z = fmaf(xv0, wxo, unhi(cp0) + go); af0[2 * jj + 1] = (__bf16)siluf(z);
        z = fmaf(xv1, wxe, unlo(cp1) + ge); af1[2 * jj]     = (__bf16)siluf(z);
        z = fmaf(xv1, wxo, unhi(cp1) + go); af1[2 * jj + 1] = (__bf16)siluf(z);
      }
#pragma unroll
      for (int nt = 0; nt < 8; ++nt) {
        bf16x8 bf = *reinterpret_cast<const bf16x8*>(&sW[nt * 16 + ar][kk * 32 + kg * 8]);
        acc[0][nt] = __builtin_amdgcn_mfma_f32_16x16x32_bf16(af0, bf, acc[0][nt], 0, 0, 0);
        acc[1][nt] = __builtin_amdgcn_mfma_f32_16x16x32_bf16(af1, bf, acc[1][nt], 0, 0, 0);
      }
    }

    // epilogue: h2 = silu(acc), pred = h2 . W3 + b3, x-update
#pragma unroll
    for (int t2 = 0; t2 < 2; ++t2) {
      float p0 = 0.f, p1 = 0.f, p2 = 0.f, p3 = 0.f;
#pragma unroll
      for (int nt = 0; nt < 8; ++nt) {
        p0 = fmaf(siluf(acc[t2][nt][0]), w3r[nt], p0);
        p1 = fmaf(siluf(acc[t2][nt][1]), w3r[nt], p1);
        p2 = fmaf(siluf(acc[t2][nt][2]), w3r[nt], p2);
        p3 = fmaf(siluf(acc[t2][nt][3]), w3r[nt], p3);
      }
#pragma unroll
      for (int m = 1; m <= 8; m <<= 1) {
        p0 += __shfl_xor(p0, m, 64);
        p1 += __shfl_xor(p1, m, 64);
        p2 += __shfl_xor(p2, m, 64);
        p3 += __shfl_xor(p3, m, 64);
      }
      const float epsm = t2 ? eps1 : eps0;
      const float e0 = __shfl(epsm, kg * 4 + 0, 64);
      const float e1 = __shfl(epsm, kg * 4 + 1, 64);
      const float e2 = __shfl(epsm, kg * 4 + 2, 64);
      const float e3 = __shfl(epsm, kg * 4 + 3, 64);
      xq[t2][0] = fmaf(c_n, e0, (xq[t2][0] - c_pred * (p0 + b3v)) * c_x);
      xq[t2][1] = fmaf(c_n, e1, (xq[t2][1] - c_pred * (p1 + b3v)) * c_x);
      xq[t2][2] = fmaf(c_n, e2, (xq[t2][2] - c_pred * (p2 + b3v)) * c_x);
      xq[t2][3] = fmaf(c_n, e3, (xq[t2][3] - c_pred * (p3 + b3v)) * c_x);
      if (ar == 0) {
#pragma unroll
        for (int r = 0; r < 4; ++r)
          sx[wv * 32 + t2 * 16 + kg * 4 + r] = xq[t2][r];
      }
    }

    acp *= __builtin_amdgcn_rcpf(alpha);  // acp_{t-1} = acp_t / alpha_t
  }

  if (ar == 0) {
#pragma unroll
    for (int t2 = 0; t2 < 2; ++t2)
#pragma unroll
      for (int r = 0; r < 4; ++r)
        out[rowW + t2 * 16 + kg * 4 + r] = xq[t2][r];
  }
}

extern "C" void kernel_launch(void* const* d_in, const int* in_sizes, int n_in,
                              void* d_out, int out_size, void* d_ws, size_t ws_size,
                              hipStream_t stream) {
  const float* ctx    = (const float*)d_in[0];
  const float* x_init = (const float*)d_in[1];
  const float* noise  = (const float*)d_in[2];
  const float* W1     = (const float*)d_in[3];
  const float* b1     = (const float*)d_in[4];
  const float* W2     = (const float*)d_in[5];
  const float* b2     = (const float*)d_in[6];
  const float* W3     = (const float*)d_in[7];
  const float* b3     = (const float*)d_in[8];
  const float* temb   = (const float*)d_in[9];
  float* out = (float*)d_out;

  diff_kernel<<<dim3(B_N / 128), dim3(256), 0, stream>>>(
      ctx, x_init, noise, W1, b1, W2, b2, W3, b3, temb, out);
}

// Round 2
// 2843.259 us; speedup vs baseline: 2.7463x; 2.7463x over previous
//
#include <hip/hip_runtime.h>

#define B_N 262144
#define T_STEPS 100
#define BETA_START 1e-4f
#define BETA_END 0.02f

typedef __bf16 bf16x8 __attribute__((ext_vector_type(8)));
typedef float f32x4 __attribute__((ext_vector_type(4)));

__device__ __forceinline__ float siluf(float z) {
  // z * sigmoid(z); native v_exp + v_rcp (2 trans ops)
  float e = __expf(-z);
  return z * __builtin_amdgcn_rcpf(1.0f + e);
}

__device__ __forceinline__ unsigned bbits(float f) {
  __bf16 h = (__bf16)f;
  return (unsigned)__builtin_bit_cast(unsigned short, h);
}
__device__ __forceinline__ unsigned pack2(float lo, float hi) {
  return bbits(lo) | (bbits(hi) << 16);
}
__device__ __forceinline__ float unlo(unsigned u) { return __uint_as_float(u << 16); }
__device__ __forceinline__ float unhi(unsigned u) { return __uint_as_float(u & 0xffff0000u); }

// Block: 256 threads = 4 waves; each wave owns 32 rows (2x 16-row MFMA tiles).
// Grid: B_N/128 = 2048 blocks.
// launch_bounds(256,1): full 512-reg unified budget -> NO spills (round-1 spilled
// ~500B/thread/step of scratch = 26 GB HBM traffic at (256,2)).
__global__ __launch_bounds__(256, 1) void diff_kernel(
    const float* __restrict__ ctx, const float* __restrict__ x_init,
    const float* __restrict__ noise, const float* __restrict__ W1,
    const float* __restrict__ b1, const float* __restrict__ W2,
    const float* __restrict__ b2, const float* __restrict__ W3,
    const float* __restrict__ b3, const float* __restrict__ temb,
    float* __restrict__ out) {
  __shared__ alignas(16) unsigned short sW[128][136];  // W^T, bf16 bits, padded
  __shared__ float sx[128];                            // per-row x broadcast
  __shared__ alignas(8) unsigned swxt[128];            // pack2(w1x[c], w1t[c])
  __shared__ float sb2[128];
  __shared__ float sw3[128];

  const int tid = threadIdx.x;
  const int lane = tid & 63;
  const int wv = tid >> 6;   // wave 0..3
  const int ar = lane & 15;  // A-frag row / C-frag col-low
  const int kg = lane >> 4;  // 0..3 k-group
  const int rowW = blockIdx.x * 128 + wv * 32;

  // ---- stage W1[:128]^T as bf16; stage small per-step constant tables ----
  for (int i = tid; i < 128 * 128; i += 256) {
    int k = i >> 7, n = i & 127;
    sW[n][k] = (unsigned short)bbits(W1[i]);
  }
  if (tid < 128) {
    swxt[tid] = pack2(W1[128 * 128 + tid], W1[129 * 128 + tid]);
    sb2[tid] = b2[tid];
    sw3[tid] = W3[tid];
  }
  __syncthreads();

  // ---- C1 = ctx @ W1[:128] + b1 (bf16 MFMA) ----
  f32x4 acc[2][8];
#pragma unroll
  for (int nt = 0; nt < 8; ++nt) {
    float b1c = b1[nt * 16 + ar];
    acc[0][nt] = (f32x4){b1c, b1c, b1c, b1c};
    acc[1][nt] = acc[0][nt];
  }

  {
    bf16x8 caf[2][4];
#pragma unroll
    for (int t2 = 0; t2 < 2; ++t2) {
      const float* crow = ctx + (size_t)(rowW + t2 * 16 + ar) * 128;
#pragma unroll
      for (int kk = 0; kk < 4; ++kk)
#pragma unroll
        for (int j = 0; j < 8; ++j)
          caf[t2][kk][j] = (__bf16)crow[kk * 32 + kg * 8 + j];
    }
#pragma unroll
    for (int kk = 0; kk < 4; ++kk)
#pragma unroll
      for (int nt = 0; nt < 8; ++nt) {
        bf16x8 bf = *reinterpret_cast<const bf16x8*>(&sW[nt * 16 + ar][kk * 32 + kg * 8]);
        acc[0][nt] = __builtin_amdgcn_mfma_f32_16x16x32_bf16(caf[0][kk], bf, acc[0][nt], 0, 0, 0);
        acc[1][nt] = __builtin_amdgcn_mfma_f32_16x16x32_bf16(caf[1][kk], bf, acc[1][nt], 0, 0, 0);
      }
  }
  __syncthreads();  // all waves done reading W1^T from LDS

  // ---- transpose C-layout -> A-layout via per-wave LDS scratch; pack bf16 pairs ----
  unsigned c1p[2][4][4];
  {
    float* scr = reinterpret_cast<float*>(&sW[0][0]) + wv * 2112;  // 16x132 f32 per wave
#pragma unroll
    for (int t2 = 0; t2 < 2; ++t2) {
#pragma unroll
      for (int nt = 0; nt < 8; ++nt)
#pragma unroll
        for (int r = 0; r < 4; ++r)
          scr[(kg * 4 + r) * 132 + nt * 16 + ar] = acc[t2][nt][r];
      asm volatile("s_waitcnt lgkmcnt(0)" ::: "memory");
#pragma unroll
      for (int kk = 0; kk < 4; ++kk)
#pragma unroll
        for (int jj = 0; jj < 4; ++jj) {
          float f0 = scr[ar * 132 + kk * 32 + kg * 8 + jj * 2];
          float f1 = scr[ar * 132 + kk * 32 + kg * 8 + jj * 2 + 1];
          c1p[t2][kk][jj] = pack2(f0, f1);
        }
      asm volatile("s_waitcnt lgkmcnt(0)" ::: "memory");
    }
  }
  __syncthreads();  // scratch reads done

  // ---- stage W2^T as bf16 ----
  for (int i = tid; i < 128 * 128; i += 256) {
    int k = i >> 7, n = i & 127;
    sW[n][k] = (unsigned short)bbits(W2[i]);
  }

  // ---- x init (every lane holds its group's 4 rows per tile) ----
  float xq[2][4];
#pragma unroll
  for (int t2 = 0; t2 < 2; ++t2)
#pragma unroll
    for (int r = 0; r < 4; ++r)
      xq[t2][r] = x_init[rowW + t2 * 16 + kg * 4 + r];
  if (ar == 0) {
#pragma unroll
    for (int t2 = 0; t2 < 2; ++t2)
#pragma unroll
      for (int r = 0; r < 4; ++r)
        sx[wv * 32 + t2 * 16 + kg * 4 + r] = xq[t2][r];
  }

  // ---- diffusion schedule: acp at t=99 via forward product ----
  const float db = (BETA_END - BETA_START) / 99.0f;
  float acp = 1.0f;
  for (int t = 0; t < T_STEPS; ++t) acp *= (1.0f - (BETA_START + (float)t * db));
  const float b3v = b3[0];
  __syncthreads();  // W2^T staged; enter barrier-free main loop

  for (int t = T_STEPS - 1; t >= 0; --t) {
    const float beta = BETA_START + (float)t * db;
    const float alpha = 1.0f - beta;
    const float c_pred = beta * __builtin_amdgcn_rsqf(1.0f - acp);
    const float c_x = __builtin_amdgcn_rsqf(alpha);
    const float c_n = (t > 0) ? __builtin_amdgcn_sqrtf(beta) : 0.0f;
    const float te = temb[t];

    // scan index: step i = 99 - t uses noise[i]
    const size_t noff = (size_t)(T_STEPS - 1 - t) * B_N + rowW;
    const float eps0 = noise[noff + ar];
    const float eps1 = noise[noff + 16 + ar];
    const float xv0 = sx[wv * 32 + ar];
    const float xv1 = sx[wv * 32 + 16 + ar];

#pragma unroll
    for (int nt = 0; nt < 8; ++nt) {
      float b2v = sb2[nt * 16 + ar];
      acc[0][nt] = (f32x4){b2v, b2v, b2v, b2v};
      acc[1][nt] = acc[0][nt];
    }

#pragma unroll
    for (int kk = 0; kk < 4; ++kk) {
      bf16x8 af0, af1;
#pragma unroll
      for (int jj = 0; jj < 4; ++jj) {
        const unsigned cp0 = c1p[0][kk][jj], cp1 = c1p[1][kk][jj];
        const uint2 wp = *reinterpret_cast<const uint2*>(&swxt[kk * 32 + kg * 8 + 2 * jj]);
        const float wxe = unlo(wp.x), wxo = unlo(wp.y);
        const float ge = te * unhi(wp.x), go = te * unhi(wp.y);
        float z;
        z = fmaf(xv0, wxe, unlo(cp0) + ge); af0[2 * jj]     = (__bf16)siluf(z);
        z = fmaf(xv0, wxo, unhi(cp0) + go); af0[2 * jj + 1] = (__bf16)siluf(z);
        z = fmaf(xv1, wxe, unlo(cp1) + ge); af1[2 * jj]     = (__bf16)siluf(z);
        z = fmaf(xv1, wxo, unhi(cp1) + go); af1[2 * jj + 1] = (__bf16)siluf(z);
      }
#pragma unroll
      for (int nt = 0; nt < 8; ++nt) {
        bf16x8 bf = *reinterpret_cast<const bf16x8*>(&sW[nt * 16 + ar][kk * 32 + kg * 8]);
        acc[0][nt] = __builtin_amdgcn_mfma_f32_16x16x32_bf16(af0, bf, acc[0][nt], 0, 0, 0);
        acc[1][nt] = __builtin_amdgcn_mfma_f32_16x16x32_bf16(af1, bf, acc[1][nt], 0, 0, 0);
      }
    }

    // epilogue: h2 = silu(acc), pred = h2 . W3 + b3, x-update
#pragma unroll
    for (int t2 = 0; t2 < 2; ++t2) {
      float p0 = 0.f, p1 = 0.f, p2 = 0.f, p3 = 0.f;
#pragma unroll
      for (int nt = 0; nt < 8; ++nt) {
        const float w3v = sw3[nt * 16 + ar];
        p0 = fmaf(siluf(acc[t2][nt][0]), w3v, p0);
        p1 = fmaf(siluf(acc[t2][nt][1]), w3v, p1);
        p2 = fmaf(siluf(acc[t2][nt][2]), w3v, p2);
        p3 = fmaf(siluf(acc[t2][nt][3]), w3v, p3);
      }
#pragma unroll
      for (int m = 1; m <= 8; m <<= 1) {
        p0 += __shfl_xor(p0, m, 64);
        p1 += __shfl_xor(p1, m, 64);
        p2 += __shfl_xor(p2, m, 64);
        p3 += __shfl_xor(p3, m, 64);
      }
      const float epsm = t2 ? eps1 : eps0;
      const float e0 = __shfl(epsm, kg * 4 + 0, 64);
      const float e1 = __shfl(epsm, kg * 4 + 1, 64);
      const float e2 = __shfl(epsm, kg * 4 + 2, 64);
      const float e3 = __shfl(epsm, kg * 4 + 3, 64);
      xq[t2][0] = fmaf(c_n, e0, (xq[t2][0] - c_pred * (p0 + b3v)) * c_x);
      xq[t2][1] = fmaf(c_n, e1, (xq[t2][1] - c_pred * (p1 + b3v)) * c_x);
      xq[t2][2] = fmaf(c_n, e2, (xq[t2][2] - c_pred * (p2 + b3v)) * c_x);
      xq[t2][3] = fmaf(c_n, e3, (xq[t2][3] - c_pred * (p3 + b3v)) * c_x);
      if (ar == 0) {
#pragma unroll
        for (int r = 0; r < 4; ++r)
          sx[wv * 32 + t2 * 16 + kg * 4 + r] = xq[t2][r];
      }
    }

    acp *= __builtin_amdgcn_rcpf(alpha);  // acp_{t-1} = acp_t / alpha_t
  }

  if (ar == 0) {
#pragma unroll
    for (int t2 = 0; t2 < 2; ++t2)
#pragma unroll
      for (int r = 0; r < 4; ++r)
        out[rowW + t2 * 16 + kg * 4 + r] = xq[t2][r];
  }
}

extern "C" void kernel_launch(void* const* d_in, const int* in_sizes, int n_in,
                              void* d_out, int out_size, void* d_ws, size_t ws_size,
                              hipStream_t stream) {
  const float* ctx    = (const float*)d_in[0];
  const float* x_init = (const float*)d_in[1];
  const float* noise  = (const float*)d_in[2];
  const float* W1     = (const float*)d_in[3];
  const float* b1     = (const float*)d_in[4];
  const float* W2     = (const float*)d_in[5];
  const float* b2     = (const float*)d_in[6];
  const float* W3     = (const float*)d_in[7];
  const float* b3     = (const float*)d_in[8];
  const float* temb   = (const float*)d_in[9];
  float* out = (float*)d_out;

  diff_kernel<<<dim3(B_N / 128), dim3(256), 0, stream>>>(
      ctx, x_init, noise, W1, b1, W2, b2, W3, b3, temb, out);
}